// Round 8
// baseline (479.273 us; speedup 1.0000x reference)
//
#include <hip/hip_runtime.h>

// Problem constants
constexpr int Bb  = 16;
constexpr int Dd  = 128;
constexpr int Tt  = 2048;
constexpr int NQn = 8;
constexpr int CSc = 1024;

constexpr int TB        = 64;     // t per block (2 tiles x 32)
constexpr int CHUNK_USH = 12288;  // 32 codes * 128 dims * 3 planes (ushorts)
constexpr int WIN_USH   = 3072;   // per-half K-window: 32 codes * 32 dims * 3 planes
constexpr int NWIN      = 64;     // windows per q per wave (16 code-chunks * 4 K-splits)

typedef __attribute__((ext_vector_type(8)))  short short8;
typedef __attribute__((ext_vector_type(4)))  float f32x4;
typedef __attribute__((ext_vector_type(16))) float f32x16;

// ---- bf16 helpers (RNE) ----
__device__ inline ushort f2bf(float f) {
    union { float f; unsigned u; } v; v.f = f;
    unsigned r = v.u + 0x7FFFu + ((v.u >> 16) & 1u);
    return (ushort)(r >> 16);
}
__device__ inline float bf2f(ushort h) {
    union { unsigned u; float f; } v; v.u = ((unsigned)h) << 16;
    return v.f;
}
__device__ inline void bsplit(float xv, ushort& h, ushort& m, ushort& l) {
    h = f2bf(xv);            float hf = bf2f(h);
    float r1 = xv - hf;      m = f2bf(r1);
    float mf = bf2f(m);      l = f2bf(r1 - mf);
}

// async global->LDS, 16 B/lane (LDS dest = wave-uniform base + lane*16)
__device__ inline void gload_lds16(const ushort* g, ushort* l) {
    __builtin_amdgcn_global_load_lds(
        (const __attribute__((address_space(1))) void*)g,
        (__attribute__((address_space(3))) void*)l, 16, 0, 0);
}

#define MFMA32(A, B, C) __builtin_amdgcn_mfma_f32_32x32x16_bf16(A, B, C, 0, 0, 0)

// ---------------------------------------------------------------------------
// Kernel 0: split codebook fp32 -> 3 bf16 planes, fragment-ordered per
// 32-code chunk, K-WINDOW-MAJOR: record index within a chunk =
//   kw*6 + p*2 + ks2   (kw = ks>>1, ks2 = ks&1), each record = 64 lanes x 8
// where lane = (dim-subgroup hi)*32 + code31, elems = dims ks*16+hi*8+j.
// A 6-KB K-window slice (one kw, one half) is contiguous. Also exact ||c||^2
// (identical summation tree/order to rounds 5-7).
// ---------------------------------------------------------------------------
__global__ __launch_bounds__(64) void split_kernel(const float* __restrict__ cb,
                                                   ushort* __restrict__ cbS,
                                                   float* __restrict__ cn) {
    const int c     = blockIdx.x * 64 + threadIdx.x;  // global code id
    const int chunk = c >> 5;
    const int c31   = c & 31;
    const float* p  = cb + (size_t)c * Dd;
    const size_t base = (size_t)chunk * CHUNK_USH;

    float s0 = 0.f, s1 = 0.f, s2 = 0.f, s3 = 0.f;
#pragma unroll
    for (int ks = 0; ks < 8; ++ks) {
#pragma unroll
        for (int hi = 0; hi < 2; ++hi) {
            const int lanew = hi * 32 + c31;
            short8 h8, m8, l8;
#pragma unroll
            for (int jj = 0; jj < 8; jj += 4) {
                float4 v = *(const float4*)(p + ks * 16 + hi * 8 + jj);
                s0 = fmaf(v.x, v.x, s0);
                s1 = fmaf(v.y, v.y, s1);
                s2 = fmaf(v.z, v.z, s2);
                s3 = fmaf(v.w, v.w, s3);
                ushort hh, mm, ll;
                bsplit(v.x, hh, mm, ll); h8[jj+0] = (short)hh; m8[jj+0] = (short)mm; l8[jj+0] = (short)ll;
                bsplit(v.y, hh, mm, ll); h8[jj+1] = (short)hh; m8[jj+1] = (short)mm; l8[jj+1] = (short)ll;
                bsplit(v.z, hh, mm, ll); h8[jj+2] = (short)hh; m8[jj+2] = (short)mm; l8[jj+2] = (short)ll;
                bsplit(v.w, hh, mm, ll); h8[jj+3] = (short)hh; m8[jj+3] = (short)mm; l8[jj+3] = (short)ll;
            }
            const int kw = ks >> 1, ks2 = ks & 1;
            *(short8*)&cbS[base + (size_t)(((kw * 6 + 0 * 2 + ks2) * 64) + lanew) * 8] = h8;
            *(short8*)&cbS[base + (size_t)(((kw * 6 + 1 * 2 + ks2) * 64) + lanew) * 8] = m8;
            *(short8*)&cbS[base + (size_t)(((kw * 6 + 2 * 2 + ks2) * 64) + lanew) * 8] = l8;
        }
    }
    cn[c] = (s0 + s1) + (s2 + s3);
}

// ---------------------------------------------------------------------------
// Kernel 1: MFMA RVQ. 256 threads = 4 waves = 2 t-tiles(32 t) x 2 code-halves.
// Grid 512 -> 2 independent blocks/CU. Residual = 3 bf16 split planes in
// registers (MFMA B operand). Codebook K-windows staged global->LDS through a
// 3-buffer 2-deep pipeline with counted vmcnt(3) + RAW s_barrier (loads stay
// in flight across barriers). Math bit-identical to round 7.
// ---------------------------------------------------------------------------
__global__ __launch_bounds__(256, 2) void rvq_mfma(const float* __restrict__ x,
                                                   const float* __restrict__ cb,
                                                   const ushort* __restrict__ cbS,
                                                   const float* __restrict__ cn_g,
                                                   float* __restrict__ out,
                                                   float* __restrict__ part) {
    __shared__ __align__(16) ushort sA[3][2][WIN_USH];   // 36 KB
    __shared__ __align__(16) float  cn_lds[CSc];         // 4 KB
    __shared__ float s_best[4][32];
    __shared__ int   s_idx[4][32];
    __shared__ float s_red[2];

    const int tid  = threadIdx.x;
    const int lane = tid & 63;
    const int w    = __builtin_amdgcn_readfirstlane(tid >> 6);
    const int tt   = w >> 1;          // t-tile 0..1
    const int h    = w & 1;           // code half
    const int l31  = lane & 31;       // t within tile / C-D column
    const int hi   = lane >> 5;       // k-subgroup 0..1

    const int t0  = blockIdx.x * TB;
    const int b   = t0 >> 11;
    const int tb0 = t0 & (Tt - 1);
    const int tg  = tb0 + tt * 32 + l31;
    const size_t xbase = (size_t)b * Dd * Tt;

    // ---- residual state: 3 bf16 planes; lane owns dims ks*16+hi*8+j of t=tg
    short8 Bf[3][8];
    float rn;
    {
        float p0 = 0.f, p1 = 0.f, p2 = 0.f, p3 = 0.f;
#pragma unroll
        for (int ks = 0; ks < 8; ++ks) {
            short8 h8, m8, l8;
#pragma unroll
            for (int j = 0; j < 8; ++j) {
                float v = x[xbase + (size_t)(ks * 16 + hi * 8 + j) * Tt + tg];
                ushort hh, mm, ll;
                bsplit(v, hh, mm, ll);
                h8[j] = (short)hh; m8[j] = (short)mm; l8[j] = (short)ll;
                if ((j & 3) == 0)      p0 = fmaf(v, v, p0);
                else if ((j & 3) == 1) p1 = fmaf(v, v, p1);
                else if ((j & 3) == 2) p2 = fmaf(v, v, p2);
                else                   p3 = fmaf(v, v, p3);
            }
            Bf[0][ks] = h8; Bf[1][ks] = m8; Bf[2][ks] = l8;
        }
        float rnp = (p0 + p1) + (p2 + p3);
        rnp += __shfl_xor(rnp, 32, 64);
        rn = rnp;
    }

    float loss_acc = 0.f;

#pragma unroll 1
    for (int q = 0; q < NQn; ++q) {
        // stage ||c||^2 for this quantizer (256 threads x 16 B)
        *(f32x4*)&cn_lds[tid * 4] = *(const f32x4*)&cn_g[(size_t)q * CSc + tid * 4];

        // staging: wave w copies 3 KB of the 12-KB window pair
        //   region hh = w>>1 (code half), segment seg = w&1
        auto STAGE = [&](int ct2, int bufb) {
            const int cc2 = ct2 >> 2, kw2 = ct2 & 3;
            const int hh = w >> 1, seg = w & 1;
            const int gc = q * 32 + hh * 16 + cc2;
            const ushort* g = cbS + (size_t)gc * CHUNK_USH + kw2 * WIN_USH +
                              seg * 1536 + lane * 8;
            ushort* dl = &sA[bufb][hh][seg * 1536];
#pragma unroll
            for (int i = 0; i < 3; ++i) gload_lds16(g + i * 512, dl + i * 512);
        };

        // prologue: windows 0,1 into bufs 0,1; wait w0 (3 left = w1's loads)
        STAGE(0, 0);
        STAGE(1, 1);
        asm volatile("s_waitcnt vmcnt(3) lgkmcnt(0)" ::: "memory");
        __builtin_amdgcn_s_barrier();
        asm volatile("" ::: "memory");

        float best = 3.4e38f;
        int   bidx = 0;
        f32x16 accA, accB;
        int s = 0;   // cc % 3

#pragma unroll 1
        for (int cc = 0; cc < 16; ++cc) {
#pragma unroll
            for (int kw = 0; kw < 4; ++kw) {
                const int ct = cc * 4 + kw;
                int buf = s + kw; if (buf >= 3) buf -= 3; if (buf >= 3) buf -= 3;

                if (kw == 0) {
                    accA = (f32x16){0.f,0.f,0.f,0.f,0.f,0.f,0.f,0.f,
                                    0.f,0.f,0.f,0.f,0.f,0.f,0.f,0.f};
                    accB = accA;
                }

                // 2-deep prefetch: issue window ct+2
                const bool iss = (ct + 2) < NWIN;
                if (iss) {
                    int b2 = buf + 2; if (b2 >= 3) b2 -= 3;
                    STAGE(ct + 2, b2);
                }

                // compute window ct (12 MFMA), conflict-free lane-linear reads
                const ushort* ab = &sA[buf][h][0];
                __builtin_amdgcn_s_setprio(1);
#pragma unroll
                for (int ks2 = 0; ks2 < 2; ++ks2) {
                    const int ks = kw * 2 + ks2;
                    short8 Ah = *(const short8*)&ab[(size_t)((0 * 2 + ks2) * 64 + lane) * 8];
                    short8 Am = *(const short8*)&ab[(size_t)((1 * 2 + ks2) * 64 + lane) * 8];
                    short8 Al = *(const short8*)&ab[(size_t)((2 * 2 + ks2) * 64 + lane) * 8];
                    accA = MFMA32(Ah, Bf[0][ks], accA);   // HH
                    accB = MFMA32(Am, Bf[1][ks], accB);   // MM
                    accA = MFMA32(Ah, Bf[1][ks], accA);   // H M_r
                    accB = MFMA32(Ah, Bf[2][ks], accB);   // H L_r
                    accA = MFMA32(Am, Bf[0][ks], accA);   // M H_r
                    accB = MFMA32(Al, Bf[0][ks], accB);   // L H_r
                }
                __builtin_amdgcn_s_setprio(0);

                if (kw == 3) {
                    f32x16 accT = accA + accB;
                    const int cq = h * 512 + cc * 32;
#pragma unroll
                    for (int blk = 0; blk < 4; ++blk) {
                        f32x4 cn4 = *(const f32x4*)&cn_lds[cq + blk * 8 + hi * 4];
#pragma unroll
                        for (int e = 0; e < 4; ++e) {
                            // C/D: code = (reg&3)+8*(reg>>2)+4*hi, col = t
                            float dd = fmaf(-2.f, accT[blk * 4 + e], rn + cn4[e]);
                            int cid = cq + blk * 8 + hi * 4 + e;
                            if (dd < best) { best = dd; bidx = cid; }  // strict <
                        }
                    }
                }

                // counted wait: keep the just-issued 3 loads in flight
                if (iss) asm volatile("s_waitcnt vmcnt(3)" ::: "memory");
                else     asm volatile("s_waitcnt vmcnt(0)" ::: "memory");
                __builtin_amdgcn_s_barrier();
                asm volatile("" ::: "memory");
            }
            ++s; if (s == 3) s = 0;
        }

        // ---- argmin: combine two k-subgroups (same t), lexicographic ----
        {
            float ob = __shfl_xor(best, 32, 64);
            int   oi = __shfl_xor(bidx, 32, 64);
            if (ob < best || (ob == best && oi < bidx)) { best = ob; bidx = oi; }
        }
        if (hi == 0) { s_best[w][l31] = best; s_idx[w][l31] = bidx; }
        __syncthreads();
        // combine with partner half (lex -> lowest index wins ties)
        {
            float ob = s_best[w ^ 1][l31];
            int   oi = s_idx[w ^ 1][l31];
            if (ob < best || (ob == best && oi < bidx)) { best = ob; bidx = oi; }
        }
        const int g = bidx;

        // ---- residual update: reconstruct H+M+L, subtract fp32 code, re-split
        {
            const float* cp = cb + ((size_t)q * CSc + g) * Dd + hi * 8;
            float q0 = 0.f, q1 = 0.f, q2 = 0.f, q3 = 0.f;
#pragma unroll
            for (int ks = 0; ks < 8; ++ks) {
                short8 h8 = Bf[0][ks], m8 = Bf[1][ks], l8 = Bf[2][ks];
                float4 ca  = *(const float4*)(cp + ks * 16);
                float4 cb4 = *(const float4*)(cp + ks * 16 + 4);
                float nv0 = ((bf2f((ushort)h8[0]) + bf2f((ushort)m8[0])) + bf2f((ushort)l8[0])) - ca.x;
                float nv1 = ((bf2f((ushort)h8[1]) + bf2f((ushort)m8[1])) + bf2f((ushort)l8[1])) - ca.y;
                float nv2 = ((bf2f((ushort)h8[2]) + bf2f((ushort)m8[2])) + bf2f((ushort)l8[2])) - ca.z;
                float nv3 = ((bf2f((ushort)h8[3]) + bf2f((ushort)m8[3])) + bf2f((ushort)l8[3])) - ca.w;
                float nv4 = ((bf2f((ushort)h8[4]) + bf2f((ushort)m8[4])) + bf2f((ushort)l8[4])) - cb4.x;
                float nv5 = ((bf2f((ushort)h8[5]) + bf2f((ushort)m8[5])) + bf2f((ushort)l8[5])) - cb4.y;
                float nv6 = ((bf2f((ushort)h8[6]) + bf2f((ushort)m8[6])) + bf2f((ushort)l8[6])) - cb4.z;
                float nv7 = ((bf2f((ushort)h8[7]) + bf2f((ushort)m8[7])) + bf2f((ushort)l8[7])) - cb4.w;
                q0 = fmaf(nv0, nv0, q0); q1 = fmaf(nv1, nv1, q1);
                q2 = fmaf(nv2, nv2, q2); q3 = fmaf(nv3, nv3, q3);
                q0 = fmaf(nv4, nv4, q0); q1 = fmaf(nv5, nv5, q1);
                q2 = fmaf(nv6, nv6, q2); q3 = fmaf(nv7, nv7, q3);
                short8 nh, nm, nl;
                ushort hh, mm, ll;
                bsplit(nv0, hh, mm, ll); nh[0] = (short)hh; nm[0] = (short)mm; nl[0] = (short)ll;
                bsplit(nv1, hh, mm, ll); nh[1] = (short)hh; nm[1] = (short)mm; nl[1] = (short)ll;
                bsplit(nv2, hh, mm, ll); nh[2] = (short)hh; nm[2] = (short)mm; nl[2] = (short)ll;
                bsplit(nv3, hh, mm, ll); nh[3] = (short)hh; nm[3] = (short)mm; nl[3] = (short)ll;
                bsplit(nv4, hh, mm, ll); nh[4] = (short)hh; nm[4] = (short)mm; nl[4] = (short)ll;
                bsplit(nv5, hh, mm, ll); nh[5] = (short)hh; nm[5] = (short)mm; nl[5] = (short)ll;
                bsplit(nv6, hh, mm, ll); nh[6] = (short)hh; nm[6] = (short)mm; nl[6] = (short)ll;
                bsplit(nv7, hh, mm, ll); nh[7] = (short)hh; nm[7] = (short)mm; nl[7] = (short)ll;
                Bf[0][ks] = nh; Bf[1][ks] = nm; Bf[2][ks] = nl;
            }
            float rnn = (q0 + q1) + (q2 + q3);
            rnn += __shfl_xor(rnn, 32, 64);
            rn = rnn;                       // ||r||^2 for next stage
            if (h == 0) loss_acc += rnn;    // both hi lanes count -> x2
        }
    }

    // ---- epilogue: q_sum = x0 - r_final (h==0 waves; state identical) ----
    if (h == 0) {
#pragma unroll
        for (int ks = 0; ks < 8; ++ks) {
            short8 h8 = Bf[0][ks], m8 = Bf[1][ks], l8 = Bf[2][ks];
#pragma unroll
            for (int j = 0; j < 8; ++j) {
                size_t off = xbase + (size_t)(ks * 16 + hi * 8 + j) * Tt + tg;
                out[off] = x[off] -
                    ((bf2f((ushort)h8[j]) + bf2f((ushort)m8[j])) + bf2f((ushort)l8[j]));
            }
        }
        float ls = loss_acc;
#pragma unroll
        for (int off = 32; off > 0; off >>= 1) ls += __shfl_down(ls, off, 64);
        if (lane == 0) s_red[tt] = ls;
    }
    __syncthreads();
    if (tid == 0)
        part[blockIdx.x] = 0.5f * (s_red[0] + s_red[1]);
}

// ---------------------------------------------------------------------------
// Kernel 2: deterministic loss reduction (32 block-partials per batch element)
// ---------------------------------------------------------------------------
__global__ __launch_bounds__(64) void loss_kernel(const float* __restrict__ part,
                                                  float* __restrict__ out_loss) {
    int b = threadIdx.x;
    if (b < Bb) {
        float s = 0.f;
        const int ppb = Tt / TB;  // 32
        for (int k = 0; k < ppb; ++k) s += part[b * ppb + k];
        out_loss[b] = s * (1.0f / ((float)Dd * (float)Tt));
    }
}

// ---------------------------------------------------------------------------
extern "C" void kernel_launch(void* const* d_in, const int* in_sizes, int n_in,
                              void* d_out, int out_size, void* d_ws, size_t ws_size,
                              hipStream_t stream) {
    const float* x  = (const float*)d_in[0];   // [B, D, T]
    const float* cb = (const float*)d_in[1];   // [NQ, CS, D]
    float* out = (float*)d_out;                // [B*D*T] q_sum ++ [B] loss_sum

    // workspace: cn[8192] f32 | part[512] f32 | cbS fragment-ordered (6.3 MB)
    float*  cn   = (float*)d_ws;
    float*  part = cn + NQn * CSc;
    ushort* cbS  = (ushort*)(part + 512);

    split_kernel<<<(NQn * CSc) / 64, 64, 0, stream>>>(cb, cbS, cn);

    const int nblocks = (Bb * Tt) / TB;  // 512
    rvq_mfma<<<nblocks, 256, 0, stream>>>(x, cb, cbS, cn, out, part);

    loss_kernel<<<1, 64, 0, stream>>>(part, out + (size_t)Bb * Dd * Tt);
}

// Round 9
// 281.572 us; speedup vs baseline: 1.7021x; 1.7021x over previous
//
#include <hip/hip_runtime.h>

// Problem constants
constexpr int Bb  = 16;
constexpr int Dd  = 128;
constexpr int Tt  = 2048;
constexpr int NQn = 8;
constexpr int CSc = 1024;

constexpr int TB   = 128;   // t per block
constexpr int NCHQ = 16;    // 32-code chunks per half per quantizer
constexpr int CHH  = 8192;  // _Float16 per chunk: 32 codes * 128 d * 2 planes (16 KB)

typedef _Float16 half8 __attribute__((ext_vector_type(8)));
typedef __attribute__((ext_vector_type(4)))  float f32x4;
typedef __attribute__((ext_vector_type(16))) float f32x16;

// ---- scaled f16 2-plane split: x ~= H + M'*2^-12 (~22 mantissa bits) ----
// |x| < 2^-14 forces H=0 so the MFMA never sees a subnormal H; M' = f16(e*4096)
// is then normal and captures the value at full f16 precision.
__device__ inline void fsplit(float xv, _Float16& h, _Float16& m) {
    _Float16 hh = (__builtin_fabsf(xv) < 6.103515625e-05f) ? (_Float16)0.0f
                                                           : (_Float16)xv;
    float e = xv - (float)hh;
    h = hh;
    m = (_Float16)(e * 4096.0f);
}
__device__ inline float frec(_Float16 h, _Float16 m) {
    return fmaf((float)m, 2.44140625e-4f, (float)h);   // exact in fp32
}

// async global->LDS, 16 B/lane (LDS dest = wave-uniform base + lane*16)
__device__ inline void gload_lds16(const _Float16* g, _Float16* l) {
    __builtin_amdgcn_global_load_lds(
        (const __attribute__((address_space(1))) void*)g,
        (__attribute__((address_space(3))) void*)l, 16, 0, 0);
}

#define MFMAH(A, B, C) __builtin_amdgcn_mfma_f32_32x32x16_f16(A, B, C, 0, 0, 0)

// ---------------------------------------------------------------------------
// Kernel 0: split codebook fp32 -> 2 f16 planes (H, M'), fragment-ordered per
// 32-code chunk for mfma_32x32x16: record (p, ks, lane) holds
// code = chunk*32 + (lane&31), dims ks*16 + (lane>>5)*8 + j.
// Also exact fp32 ||c||^2 (same tree as rounds 5-8).
// ---------------------------------------------------------------------------
__global__ __launch_bounds__(64) void split_kernel(const float* __restrict__ cb,
                                                   _Float16* __restrict__ cbS,
                                                   float* __restrict__ cn) {
    const int c     = blockIdx.x * 64 + threadIdx.x;  // global code id
    const int chunk = c >> 5;
    const int c31   = c & 31;
    const float* p  = cb + (size_t)c * Dd;
    const size_t base = (size_t)chunk * CHH;

    float s0 = 0.f, s1 = 0.f, s2 = 0.f, s3 = 0.f;
#pragma unroll
    for (int ks = 0; ks < 8; ++ks) {
#pragma unroll
        for (int hi2 = 0; hi2 < 2; ++hi2) {
            const int lanew = hi2 * 32 + c31;
            half8 h8, m8;
#pragma unroll
            for (int jj = 0; jj < 8; jj += 4) {
                float4 v = *(const float4*)(p + ks * 16 + hi2 * 8 + jj);
                s0 = fmaf(v.x, v.x, s0);
                s1 = fmaf(v.y, v.y, s1);
                s2 = fmaf(v.z, v.z, s2);
                s3 = fmaf(v.w, v.w, s3);
                _Float16 hh, mm;
                fsplit(v.x, hh, mm); h8[jj + 0] = hh; m8[jj + 0] = mm;
                fsplit(v.y, hh, mm); h8[jj + 1] = hh; m8[jj + 1] = mm;
                fsplit(v.z, hh, mm); h8[jj + 2] = hh; m8[jj + 2] = mm;
                fsplit(v.w, hh, mm); h8[jj + 3] = hh; m8[jj + 3] = mm;
            }
            *(half8*)&cbS[base + (size_t)((0 * 8 + ks) * 64 + lanew) * 8] = h8;
            *(half8*)&cbS[base + (size_t)((8 + ks) * 64 + lanew) * 8]     = m8;
        }
    }
    cn[c] = (s0 + s1) + (s2 + s3);
}

// ---------------------------------------------------------------------------
// Kernel 1: MFMA RVQ. 512 threads = 8 waves = 4 t-tiles(32 t) x 2 code-halves
// (round-7 structure). Residual = 2 f16 planes in registers (MFMA B operand).
// Codebook chunks staged global->LDS via 3-buffer 2-deep pipeline with
// COUNTED vmcnt(4) + raw s_barrier (loads stay in flight across barriers).
// Distances via 3-pass scaled-f16 MFMA: dot = accA + 2^-12 (accB1 + accB2).
// ---------------------------------------------------------------------------
__global__ __launch_bounds__(512) void rvq_mfma(const float* __restrict__ x,
                                                const float* __restrict__ cb,
                                                const _Float16* __restrict__ cbS,
                                                const float* __restrict__ cn_g,
                                                float* __restrict__ out,
                                                float* __restrict__ part) {
    __shared__ __align__(16) _Float16 sA[3][2][CHH];   // 96 KB
    __shared__ __align__(16) float    cn_lds[CSc];     // 4 KB
    __shared__ float s_best[8][32];
    __shared__ int   s_idx[8][32];
    __shared__ float s_red[4];

    const int tid  = threadIdx.x;
    const int lane = tid & 63;
    const int w    = __builtin_amdgcn_readfirstlane(tid >> 6);
    const int tt   = w >> 1;          // t-tile 0..3
    const int h    = w & 1;           // code half
    const int l31  = lane & 31;       // t within tile / C-D column
    const int hi   = lane >> 5;       // k-subgroup 0..1

    const int t0  = blockIdx.x * TB;
    const int b   = t0 >> 11;
    const int tb0 = t0 & (Tt - 1);
    const int tg  = tb0 + tt * 32 + l31;
    const size_t xbase = (size_t)b * Dd * Tt;

    // ---- residual state: 2 f16 planes; lane owns dims ks*16+hi*8+j of t=tg
    half8 Bh[8], Bm[8];
    float rn;
    {
        float p0 = 0.f, p1 = 0.f, p2 = 0.f, p3 = 0.f;
#pragma unroll
        for (int ks = 0; ks < 8; ++ks) {
            half8 h8, m8;
#pragma unroll
            for (int j = 0; j < 8; ++j) {
                float v = x[xbase + (size_t)(ks * 16 + hi * 8 + j) * Tt + tg];
                _Float16 hh, mm;
                fsplit(v, hh, mm);
                h8[j] = hh; m8[j] = mm;
                if ((j & 3) == 0)      p0 = fmaf(v, v, p0);
                else if ((j & 3) == 1) p1 = fmaf(v, v, p1);
                else if ((j & 3) == 2) p2 = fmaf(v, v, p2);
                else                   p3 = fmaf(v, v, p3);
            }
            Bh[ks] = h8; Bm[ks] = m8;
        }
        float rnp = (p0 + p1) + (p2 + p3);
        rnp += __shfl_xor(rnp, 32, 64);
        rn = rnp;
    }

    float loss_acc = 0.f;

#pragma unroll 1
    for (int q = 0; q < NQn; ++q) {
        // stage ||c||^2 for this quantizer (512 threads x 8 B)
        *(float2*)&cn_lds[tid * 2] = *(const float2*)&cn_g[(size_t)q * CSc + tid * 2];

        // staging: wave w copies 4 KB of its half's 16-KB chunk
        auto STAGE = [&](int ct, int bb) {
            const int gc = q * 32 + h * 16 + ct;
            const _Float16* g = cbS + (size_t)gc * CHH + tt * 2048 + lane * 8;
            _Float16* dl = &sA[bb][h][tt * 2048];
#pragma unroll
            for (int i = 0; i < 4; ++i) gload_lds16(g + i * 512, dl + i * 512);
        };

        // prologue: chunks 0,1 -> bufs 0,1; wait chunk 0 (keep chunk 1 in flight)
        STAGE(0, 0);
        STAGE(1, 1);
        asm volatile("s_waitcnt vmcnt(4) lgkmcnt(0)" ::: "memory");
        __builtin_amdgcn_s_barrier();
        asm volatile("" ::: "memory");

        float best = 3.4e38f;
        int   bidx = 0;
        int   buf  = 0;

#pragma unroll 1
        for (int ct = 0; ct < NCHQ; ++ct) {
            const bool iss = (ct + 2) < NCHQ;
            if (iss) {                       // 2-deep prefetch into buf+2 (mod 3)
                int b2 = buf - 1; if (b2 < 0) b2 = 2;
                STAGE(ct + 2, b2);
            }

            // A-fragments: conflict-free lane-linear ds_read_b128
            const _Float16* ab = &sA[buf][h][0];
            half8 Ah[8], Am[8];
#pragma unroll
            for (int ks = 0; ks < 8; ++ks) {
                Ah[ks] = *(const half8*)&ab[(size_t)((0 * 8 + ks) * 64 + lane) * 8];
                Am[ks] = *(const half8*)&ab[(size_t)((8 + ks) * 64 + lane) * 8];
            }

            f32x16 accA  = {0.f,0.f,0.f,0.f,0.f,0.f,0.f,0.f,0.f,0.f,0.f,0.f,0.f,0.f,0.f,0.f};
            f32x16 accB1 = accA, accB2 = accA;
            __builtin_amdgcn_s_setprio(1);
#pragma unroll
            for (int ks = 0; ks < 8; ++ks) {
                accA  = MFMAH(Ah[ks], Bh[ks], accA);    // H_c * H_r
                accB1 = MFMAH(Ah[ks], Bm[ks], accB1);   // H_c * M'_r  (2^12-scaled)
                accB2 = MFMAH(Am[ks], Bh[ks], accB2);   // M'_c * H_r  (2^12-scaled)
            }
            __builtin_amdgcn_s_setprio(0);

            const int cq = h * 512 + ct * 32;
#pragma unroll
            for (int blk = 0; blk < 4; ++blk) {
                f32x4 cn4 = *(const f32x4*)&cn_lds[cq + blk * 8 + hi * 4];
#pragma unroll
                for (int e = 0; e < 4; ++e) {
                    const int i = blk * 4 + e;
                    // dot = accA + 2^-12 (accB1 + accB2)
                    float dotv = fmaf(accB1[i] + accB2[i], 2.44140625e-4f, accA[i]);
                    // C/D: code = (reg&3)+8*(reg>>2)+4*hi, col = t  (r7-verified)
                    float dd = fmaf(-2.f, dotv, rn + cn4[e]);
                    int cid = cq + blk * 8 + hi * 4 + e;
                    if (dd < best) { best = dd; bidx = cid; }   // strict <
                }
            }

            // counted wait: the just-issued prefetch (4 loads) stays in flight
            if (iss) asm volatile("s_waitcnt vmcnt(4)" ::: "memory");
            else     asm volatile("s_waitcnt vmcnt(0)" ::: "memory");
            __builtin_amdgcn_s_barrier();
            asm volatile("" ::: "memory");

            ++buf; if (buf == 3) buf = 0;
        }

        // ---- argmin: combine two k-subgroups (same t), lexicographic ----
        {
            float ob = __shfl_xor(best, 32, 64);
            int   oi = __shfl_xor(bidx, 32, 64);
            if (ob < best || (ob == best && oi < bidx)) { best = ob; bidx = oi; }
        }
        if (hi == 0) { s_best[w][l31] = best; s_idx[w][l31] = bidx; }
        __syncthreads();
        // combine with partner half (lex -> lowest index wins ties)
        {
            float ob = s_best[w ^ 1][l31];
            int   oi = s_idx[w ^ 1][l31];
            if (ob < best || (ob == best && oi < bidx)) { best = ob; bidx = oi; }
        }
        const int g = bidx;

        // ---- residual update: reconstruct H+M'*2^-12, subtract fp32 code,
        //      re-split; accumulate loss = ||r_new||^2 ----
        {
            const float* cp = cb + ((size_t)q * CSc + g) * Dd + hi * 8;
            float q0 = 0.f, q1 = 0.f, q2 = 0.f, q3 = 0.f;
#pragma unroll
            for (int ks = 0; ks < 8; ++ks) {
                f32x4 ca  = *(const f32x4*)(cp + ks * 16);
                f32x4 cb4 = *(const f32x4*)(cp + ks * 16 + 4);
                half8 h8 = Bh[ks], m8 = Bm[ks];
                half8 nh, nm;
#pragma unroll
                for (int j = 0; j < 8; ++j) {
                    float cj = (j < 4) ? ca[j] : cb4[j - 4];
                    float nv = frec(h8[j], m8[j]) - cj;
                    if ((j & 3) == 0)      q0 = fmaf(nv, nv, q0);
                    else if ((j & 3) == 1) q1 = fmaf(nv, nv, q1);
                    else if ((j & 3) == 2) q2 = fmaf(nv, nv, q2);
                    else                   q3 = fmaf(nv, nv, q3);
                    _Float16 hh, mm;
                    fsplit(nv, hh, mm);
                    nh[j] = hh; nm[j] = mm;
                }
                Bh[ks] = nh; Bm[ks] = nm;
            }
            float rnn = (q0 + q1) + (q2 + q3);
            rnn += __shfl_xor(rnn, 32, 64);
            rn = rnn;                       // ||r||^2 for next stage
            if (h == 0) loss_acc += rnn;    // both hi lanes count -> x2
        }
    }

    // ---- epilogue: q_sum = x0 - r_final (h==0 waves; state identical) ----
    if (h == 0) {
#pragma unroll
        for (int ks = 0; ks < 8; ++ks) {
            half8 h8 = Bh[ks], m8 = Bm[ks];
#pragma unroll
            for (int j = 0; j < 8; ++j) {
                size_t off = xbase + (size_t)(ks * 16 + hi * 8 + j) * Tt + tg;
                out[off] = x[off] - frec(h8[j], m8[j]);
            }
        }
        float ls = loss_acc;
#pragma unroll
        for (int off = 32; off > 0; off >>= 1) ls += __shfl_down(ls, off, 64);
        if (lane == 0) s_red[tt] = ls;
    }
    __syncthreads();
    if (tid == 0)
        part[blockIdx.x] = 0.5f * ((s_red[0] + s_red[1]) + (s_red[2] + s_red[3]));
}

// ---------------------------------------------------------------------------
// Kernel 2: deterministic loss reduction (16 block-partials per batch element)
// ---------------------------------------------------------------------------
__global__ __launch_bounds__(64) void loss_kernel(const float* __restrict__ part,
                                                  float* __restrict__ out_loss) {
    int b = threadIdx.x;
    if (b < Bb) {
        float s = 0.f;
        const int ppb = Tt / TB;  // 16
        for (int k = 0; k < ppb; ++k) s += part[b * ppb + k];
        out_loss[b] = s * (1.0f / ((float)Dd * (float)Tt));
    }
}

// ---------------------------------------------------------------------------
extern "C" void kernel_launch(void* const* d_in, const int* in_sizes, int n_in,
                              void* d_out, int out_size, void* d_ws, size_t ws_size,
                              hipStream_t stream) {
    const float* x  = (const float*)d_in[0];   // [B, D, T]
    const float* cb = (const float*)d_in[1];   // [NQ, CS, D]
    float* out = (float*)d_out;                // [B*D*T] q_sum ++ [B] loss_sum

    // workspace: cn[8192] f32 | part[256] f32 | cbS 2-plane f16 (4 MB)
    float*    cn   = (float*)d_ws;
    float*    part = cn + NQn * CSc;
    _Float16* cbS  = (_Float16*)(part + 256);

    split_kernel<<<(NQn * CSc) / 64, 64, 0, stream>>>(cb, cbS, cn);

    const int nblocks = (Bb * Tt) / TB;  // 256
    rvq_mfma<<<nblocks, 512, 0, stream>>>(x, cb, cbS, cn, out, part);

    loss_kernel<<<1, 64, 0, stream>>>(part, out + (size_t)Bb * Dd * Tt);
}